// Round 8
// baseline (500.768 us; speedup 1.0000x reference)
//
#include <hip/hip_runtime.h>
#include <hip/hip_cooperative_groups.h>
#include <stdint.h>

namespace cg = cooperative_groups;

#define NN 8192
#define CC 128
#define BN_EPS 1e-5f

__device__ inline unsigned short f2bf(float f) {
    unsigned int u = __float_as_uint(f);
    unsigned int r = (u + 0x7fffu + ((u >> 16) & 1u)) >> 16;   // RNE
    return (unsigned short)r;
}

// ---------------------------------------------------------------------------
// Kernel 1a: compress binary A into a bit-transposed mask + degrees.
//   Mt[band * 8192 + i] : u64 word, bit b set iff A[band*64 + b][i] != 0
//   deg[j]              : rowsum of A[j,:] (float)
// R3-exact (proven fastest of 4 structurally different variants; R4/R6/R7
// falsified orientation/MLP/aggregate-pattern theories — the 268 MB A read
// pins at ~2.9 TB/s in all forms => this is the HBM-read roofline).
// ---------------------------------------------------------------------------
__global__ __launch_bounds__(256, 8) void k1a_mask(
        const float* __restrict__ A, unsigned long long* __restrict__ Mt,
        float* __restrict__ deg) {
    __shared__ float dred[4][64];
    const int lane = threadIdx.x & 63;
    const int wave = threadIdx.x >> 6;
    const int task = blockIdx.x * 4 + wave;     // 0..8191
    const int band = task >> 6;                 // 0..127
    const int i0   = (task & 63) << 7;          // col tile * 128
    const int j0   = band << 6;                 // row band * 64

    const uint2* Ap = reinterpret_cast<const uint2*>(A + (size_t)j0 * NN + i0) + lane;
    unsigned long long m0 = 0, m1 = 0;
    float degc = 0.0f;

    #pragma unroll 8
    for (int j = 0; j < 64; ++j) {
        uint2 v = Ap[(size_t)j * (NN / 2)];     // 0.0f or 1.0f -> bit test
        bool n0 = v.x != 0u, n1 = v.y != 0u;
        unsigned long long b0 = __ballot(n0), b1 = __ballot(n1);
        const unsigned long long bit = 1ull << j;
        if (n0) m0 |= bit;
        if (n1) m1 |= bit;
        if (lane == j) degc = (float)(__popcll(b0) + __popcll(b1));
    }

    unsigned long long* p = Mt + (size_t)band * NN + i0 + 2 * lane;
    *reinterpret_cast<ulonglong2*>(p) = make_ulonglong2(m0, m1);

    dred[wave][lane] = degc;
    __syncthreads();
    if (wave == 0) {
        float s = dred[0][lane] + dred[1][lane] + dred[2][lane] + dred[3][lane];
        atomicAdd(&deg[j0 + lane], s);
    }
}

// ---------------------------------------------------------------------------
// Kernel 1c: aggN[i,:] = (1/deg[i]) * sum_{j : A[j,i]!=0} X[j,:]
// One BLOCK per output row i; 4 waves split the 128 mask words, LDS reduce.
// (R3-exact — proven ~33 us)
// ---------------------------------------------------------------------------
__global__ __launch_bounds__(256, 8) void k1c_gather(
        const unsigned long long* __restrict__ Mt, const float* __restrict__ X,
        const float* __restrict__ deg, float* __restrict__ aggN) {
    __shared__ float red[4][128];
    const int lane = threadIdx.x & 63;
    const int wave = threadIdx.x >> 6;
    const int i = blockIdx.x;

    unsigned long long w = 0;
    if (lane < 32)
        w = Mt[(size_t)(wave * 32 + lane) * NN + i];
    float acc0 = 0.0f, acc1 = 0.0f;

    unsigned long long any = __ballot(w != 0ull);   // bits only in lanes 0..31
    while (any) {
        int q = __builtin_ctzll(any); any &= any - 1;
        unsigned long long u = __shfl(w, q);
        const float* Xq = X + (size_t)((wave * 32 + q) * 64) * CC;
        while (u) {
            int b = __builtin_ctzll(u); u &= u - 1;
            const float* xr = Xq + b * CC;
            acc0 += xr[lane];
            acc1 += xr[64 + lane];
        }
    }

    red[wave][lane]      = acc0;
    red[wave][64 + lane] = acc1;
    __syncthreads();
    if (wave == 0) {
        float s0 = red[0][lane]      + red[1][lane]      + red[2][lane]      + red[3][lane];
        float s1 = red[0][64 + lane] + red[1][64 + lane] + red[2][64 + lane] + red[3][64 + lane];
        float d  = deg[i];
        float rd = (d == 0.0f) ? 1.0f : (1.0f / d);
        aggN[(size_t)i * CC + lane]      = s0 * rd;
        aggN[(size_t)i * CC + 64 + lane] = s1 * rd;
    }
}

// ---------------------------------------------------------------------------
// Kernel 2+4 FUSED (cooperative): h = aggN@Wn^T + X@Wc^T + biases, BN stats
// via global atomics, grid.sync(), then in-register normalize+relu -> out.
// 512 blocks = exactly 2/CU x 256 CU (64 KB LDS => co-resident guaranteed).
// Saves: k4 dispatch, h write+read (8 MB), one launch gap.
// Weight staging: fused LDS Wp[swz] = bf16(Wn)|bf16(Wc)<<16, XOR ^(k&31)
// (conflict-free; verified -13.7 us in R3).
// ---------------------------------------------------------------------------
__global__ __launch_bounds__(256, 2) void k2k4_fused(
        const float* __restrict__ aggN, const float* __restrict__ X,
        const float* __restrict__ Wn, const float* __restrict__ bn,
        const float* __restrict__ Wc, const float* __restrict__ bc,
        float* __restrict__ bsum, float* __restrict__ bsq,
        const float* __restrict__ gamma, const float* __restrict__ beta,
        float* __restrict__ out) {
    __shared__ unsigned int Wp[128 * 128];      // 64 KB -> 2 blocks/CU
    const int tid = threadIdx.x;
    for (int idx = tid * 4; idx < 128 * 128; idx += 1024) {
        float4 wn4 = *reinterpret_cast<const float4*>(Wn + idx);
        float4 wc4 = *reinterpret_cast<const float4*>(Wc + idx);
        int c = idx >> 7, k0 = idx & 127;       // 4 consecutive k, same c
        #pragma unroll
        for (int q = 0; q < 4; ++q) {
            unsigned int pk = (unsigned int)f2bf((&wn4.x)[q])
                            | ((unsigned int)f2bf((&wc4.x)[q]) << 16);
            int k = k0 + q;
            Wp[(k * 128 + c) ^ (k & 31)] = pk;
        }
    }
    __syncthreads();
    const int c  = tid & 127;
    const int rg = tid >> 7;
    const int i0 = blockIdx.x * 16 + rg * 8;

    float accN[8], accC[8];
    #pragma unroll
    for (int r = 0; r < 8; ++r) { accN[r] = 0.0f; accC[r] = 0.0f; }

    float4 ar[8], xr[8], an[8], xn[8];

#define LOADK(ab_, xb_, k_) do {                                               \
    _Pragma("unroll")                                                          \
    for (int r = 0; r < 8; ++r) {                                              \
        ab_[r] = *reinterpret_cast<const float4*>(&aggN[(size_t)(i0 + r) * CC + (k_)]); \
        xb_[r] = *reinterpret_cast<const float4*>(&X[(size_t)(i0 + r) * CC + (k_)]);    \
    }                                                                          \
} while (0)

#define COMPK(ab_, xb_, k_) do {                                               \
    _Pragma("unroll")                                                          \
    for (int kk = 0; kk < 4; ++kk) {                                           \
        int kq_ = (k_) + kk;                                                   \
        unsigned int pk_ = Wp[(kq_ * 128 + c) ^ (kq_ & 31)];                   \
        float wn_ = __uint_as_float(pk_ << 16);                                \
        float wc_ = __uint_as_float(pk_ & 0xffff0000u);                        \
        _Pragma("unroll")                                                      \
        for (int r = 0; r < 8; ++r) {                                          \
            accN[r] = fmaf((&ab_[r].x)[kk], wn_, accN[r]);                     \
            accC[r] = fmaf((&xb_[r].x)[kk], wc_, accC[r]);                     \
        }                                                                      \
    }                                                                          \
} while (0)

    LOADK(ar, xr, 0);
    for (int k = 0; k < 128; k += 8) {
        LOADK(an, xn, k + 4);
        COMPK(ar, xr, k);
        if (k + 8 < 128) LOADK(ar, xr, k + 8);
        COMPK(an, xn, k + 4);
    }

    const float bnc = bn[c], bcc = bc[c];
    float hv[8];
    float sp = 0.0f, sq = 0.0f;
    #pragma unroll
    for (int r = 0; r < 8; ++r) {
        hv[r] = accN[r] + accC[r] + bnc + bcc;
        sp += hv[r]; sq += hv[r] * hv[r];
    }
    __syncthreads();                              // Wp reads done; reuse as fp32 scratch
    float* red = reinterpret_cast<float*>(Wp);
    red[rg * 128 + c]       = sp;
    red[256 + rg * 128 + c] = sq;
    __syncthreads();
    if (rg == 0) {
        atomicAdd(&bsum[c], red[c] + red[128 + c]);
        atomicAdd(&bsq[c],  red[256 + c] + red[384 + c]);
    }

    cg::this_grid().sync();                       // all partials now in bsum/bsq

    const float invN = 1.0f / 8192.0f;
    const float mu  = bsum[c] * invN;
    const float var = bsq[c] * invN - mu * mu;
    const float sc  = gamma[c] * rsqrtf(var + BN_EPS);
    const float bt  = beta[c] - mu * sc;
    #pragma unroll
    for (int r = 0; r < 8; ++r) {
        float v = hv[r] * sc + bt;
        out[(size_t)(i0 + r) * CC + c] = v > 0.0f ? v : 0.0f;
    }
}

// ---------------------------------------------------------------------------
// Fallback split path (used only if cooperative launch is rejected).
// ---------------------------------------------------------------------------
__global__ __launch_bounds__(256, 2) void k2_gemm(
        const float* __restrict__ aggN, const float* __restrict__ X,
        const float* __restrict__ Wn, const float* __restrict__ bn,
        const float* __restrict__ Wc, const float* __restrict__ bc,
        float* __restrict__ h, float* __restrict__ bsum, float* __restrict__ bsq) {
    __shared__ unsigned int Wp[128 * 128];
    const int tid = threadIdx.x;
    for (int idx = tid * 4; idx < 128 * 128; idx += 1024) {
        float4 wn4 = *reinterpret_cast<const float4*>(Wn + idx);
        float4 wc4 = *reinterpret_cast<const float4*>(Wc + idx);
        int c = idx >> 7, k0 = idx & 127;
        #pragma unroll
        for (int q = 0; q < 4; ++q) {
            unsigned int pk = (unsigned int)f2bf((&wn4.x)[q])
                            | ((unsigned int)f2bf((&wc4.x)[q]) << 16);
            int k = k0 + q;
            Wp[(k * 128 + c) ^ (k & 31)] = pk;
        }
    }
    __syncthreads();
    const int c  = tid & 127;
    const int rg = tid >> 7;
    const int i0 = blockIdx.x * 16 + rg * 8;

    float accN[8], accC[8];
    #pragma unroll
    for (int r = 0; r < 8; ++r) { accN[r] = 0.0f; accC[r] = 0.0f; }

    float4 ar[8], xr[8], an[8], xn[8];

    LOADK(ar, xr, 0);
    for (int k = 0; k < 128; k += 8) {
        LOADK(an, xn, k + 4);
        COMPK(ar, xr, k);
        if (k + 8 < 128) LOADK(ar, xr, k + 8);
        COMPK(an, xn, k + 4);
    }

    const float bnc = bn[c], bcc = bc[c];
    float sp = 0.0f, sq = 0.0f;
    #pragma unroll
    for (int r = 0; r < 8; ++r) {
        float hv = accN[r] + accC[r] + bnc + bcc;
        h[(size_t)(i0 + r) * CC + c] = hv;
        sp += hv; sq += hv * hv;
    }
    __syncthreads();
    float* red = reinterpret_cast<float*>(Wp);
    red[rg * 128 + c]       = sp;
    red[256 + rg * 128 + c] = sq;
    __syncthreads();
    if (rg == 0) {
        atomicAdd(&bsum[c], red[c] + red[128 + c]);
        atomicAdd(&bsq[c],  red[256 + c] + red[384 + c]);
    }
}

__global__ __launch_bounds__(256) void k4_bn(
        const float* __restrict__ h, const float* __restrict__ bsum,
        const float* __restrict__ bsq, const float* __restrict__ gamma,
        const float* __restrict__ beta, float* __restrict__ out) {
    const int idx = (blockIdx.x * 256 + threadIdx.x) * 4;
    const int c0  = idx & 127;
    float4 hv = *reinterpret_cast<const float4*>(h + idx);
    float4 s4 = *reinterpret_cast<const float4*>(bsum + c0);
    float4 q4 = *reinterpret_cast<const float4*>(bsq + c0);
    float4 g4 = *reinterpret_cast<const float4*>(gamma + c0);
    float4 b4 = *reinterpret_cast<const float4*>(beta + c0);
    const float invN = 1.0f / 8192.0f;
    float4 o;
    const float* hp = &hv.x; const float* sp = &s4.x; const float* qp = &q4.x;
    const float* gp = &g4.x; const float* bp = &b4.x; float* op = &o.x;
    #pragma unroll
    for (int jj = 0; jj < 4; ++jj) {
        float mu  = sp[jj] * invN;
        float var = qp[jj] * invN - mu * mu;
        float sc  = gp[jj] * rsqrtf(var + BN_EPS);
        float v   = (hp[jj] - mu) * sc + bp[jj];
        op[jj] = v > 0.0f ? v : 0.0f;
    }
    *reinterpret_cast<float4*>(out + idx) = o;
}

extern "C" void kernel_launch(void* const* d_in, const int* in_sizes, int n_in,
                              void* d_out, int out_size, void* d_ws, size_t ws_size,
                              hipStream_t stream) {
    const float* X     = (const float*)d_in[0];   // [8192,128]
    const float* A     = (const float*)d_in[1];   // [8192,8192]
    const float* Wn    = (const float*)d_in[2];   // [128,128]
    const float* bn    = (const float*)d_in[3];
    const float* Wc    = (const float*)d_in[4];
    const float* bc    = (const float*)d_in[5];
    const float* gamma = (const float*)d_in[6];
    const float* beta  = (const float*)d_in[7];
    float* out = (float*)d_out;

    // Workspace layout (12.65 MB) — identical to round 3:
    //   deg   @ 0        (32 KB, zeroed)
    //   bsum  @ 32768    (512 B, zeroed)
    //   bsq   @ 33280    (512 B, zeroed)
    //   aggN  @ 65536    (4 MB, fully written by k1c)
    //   Mt    @ 4259840  (8 MB, fully written by k1a)
    //   h     aliases Mt (fallback path only; Mt dead after k1c)
    char* ws = (char*)d_ws;
    float* deg  = (float*)(ws);
    float* bsum = (float*)(ws + 32768);
    float* bsq  = (float*)(ws + 33280);
    float* aggN = (float*)(ws + 65536);
    unsigned long long* Mt = (unsigned long long*)(ws + 4259840);
    float* h    = (float*)(ws + 4259840);

    hipMemsetAsync(d_ws, 0, 33792, stream);

    k1a_mask  <<<2048, 256, 0, stream>>>(A, Mt, deg);
    k1c_gather<<<8192, 256, 0, stream>>>(Mt, X, deg, aggN);

    void* ka[] = { (void*)&aggN, (void*)&X, (void*)&Wn, (void*)&bn,
                   (void*)&Wc, (void*)&bc, (void*)&bsum, (void*)&bsq,
                   (void*)&gamma, (void*)&beta, (void*)&out };
    hipError_t ce = hipLaunchCooperativeKernel(
        reinterpret_cast<const void*>(&k2k4_fused), dim3(512), dim3(256),
        ka, 0, stream);
    if (ce != hipSuccess) {
        k2_gemm<<<512,  256, 0, stream>>>(aggN, X, Wn, bn, Wc, bc, h, bsum, bsq);
        k4_bn  <<<1024, 256, 0, stream>>>(h, bsum, bsq, gamma, beta, out);
    }
}

// Round 9
// 445.031 us; speedup vs baseline: 1.1252x; 1.1252x over previous
//
#include <hip/hip_runtime.h>
#include <stdint.h>

#define NN 8192
#define CC 128
#define BN_EPS 1e-5f

__device__ inline unsigned short f2bf(float f) {
    unsigned int u = __float_as_uint(f);
    unsigned int r = (u + 0x7fffu + ((u >> 16) & 1u)) >> 16;   // RNE
    return (unsigned short)r;
}

// ---------------------------------------------------------------------------
// Kernel 1a: compress binary A into a bit-transposed mask + degrees.
//   Mt2[i * 128 + band] : u64 word, bit b set iff A[band*64 + b][i] != 0
//   deg[j]              : rowsum of A[j,:] (float)
// R3-exact read structure (proven fastest of 4 variants; the 268 MB A read
// pins at ~2.9 TB/s in all forms => HBM-read roofline). ONLY change: store
// layout is now column-major-by-band (Mt2[i][band]) so k1c's per-block word
// list is contiguous. Stores: 2x scattered 8-B per lane (1M total, ~1 per
// 47 CU-cycles — hidden under the 92 us read time; writes are posted).
// ---------------------------------------------------------------------------
__global__ __launch_bounds__(256, 8) void k1a_mask(
        const float* __restrict__ A, unsigned long long* __restrict__ Mt2,
        float* __restrict__ deg) {
    __shared__ float dred[4][64];
    const int lane = threadIdx.x & 63;
    const int wave = threadIdx.x >> 6;
    const int task = blockIdx.x * 4 + wave;     // 0..8191
    const int band = task >> 6;                 // 0..127
    const int i0   = (task & 63) << 7;          // col tile * 128
    const int j0   = band << 6;                 // row band * 64

    const uint2* Ap = reinterpret_cast<const uint2*>(A + (size_t)j0 * NN + i0) + lane;
    unsigned long long m0 = 0, m1 = 0;
    float degc = 0.0f;

    #pragma unroll 8
    for (int j = 0; j < 64; ++j) {
        uint2 v = Ap[(size_t)j * (NN / 2)];     // 0.0f or 1.0f -> bit test
        bool n0 = v.x != 0u, n1 = v.y != 0u;
        unsigned long long b0 = __ballot(n0), b1 = __ballot(n1);
        const unsigned long long bit = 1ull << j;
        if (n0) m0 |= bit;
        if (n1) m1 |= bit;
        if (lane == j) degc = (float)(__popcll(b0) + __popcll(b1));
    }

    const int i = i0 + 2 * lane;                // lane's two columns
    Mt2[(size_t)i * 128 + band]       = m0;
    Mt2[(size_t)(i + 1) * 128 + band] = m1;

    dred[wave][lane] = degc;
    __syncthreads();
    if (wave == 0) {
        float s = dred[0][lane] + dred[1][lane] + dred[2][lane] + dred[3][lane];
        atomicAdd(&deg[j0 + lane], s);
    }
}

// ---------------------------------------------------------------------------
// Kernel 1c: aggN[i,:] = (1/deg[i]) * sum_{j : A[j,i]!=0} X[j,:]
// One BLOCK per output row i; 4 waves split the 128 mask words, LDS reduce.
// R3-exact decode/gather; ONLY change: mask words now CONTIGUOUS
// (Mt2[i*128 + w], 1 KB per block, 8 cache lines) instead of 128 lines at
// 64-KB stride (was 134 MB of scattered L3 line traffic => ~33 us; now 8 MB).
// ---------------------------------------------------------------------------
__global__ __launch_bounds__(256, 8) void k1c_gather(
        const unsigned long long* __restrict__ Mt2, const float* __restrict__ X,
        const float* __restrict__ deg, float* __restrict__ aggN) {
    __shared__ float red[4][128];
    const int lane = threadIdx.x & 63;
    const int wave = threadIdx.x >> 6;
    const int i = blockIdx.x;

    unsigned long long w = 0;
    if (lane < 32)
        w = Mt2[(size_t)i * 128 + wave * 32 + lane];
    float acc0 = 0.0f, acc1 = 0.0f;

    unsigned long long any = __ballot(w != 0ull);   // bits only in lanes 0..31
    while (any) {
        int q = __builtin_ctzll(any); any &= any - 1;
        unsigned long long u = __shfl(w, q);
        const float* Xq = X + (size_t)((wave * 32 + q) * 64) * CC;
        while (u) {
            int b = __builtin_ctzll(u); u &= u - 1;
            const float* xr = Xq + b * CC;
            acc0 += xr[lane];
            acc1 += xr[64 + lane];
        }
    }

    red[wave][lane]      = acc0;
    red[wave][64 + lane] = acc1;
    __syncthreads();
    if (wave == 0) {
        float s0 = red[0][lane]      + red[1][lane]      + red[2][lane]      + red[3][lane];
        float s1 = red[0][64 + lane] + red[1][64 + lane] + red[2][64 + lane] + red[3][64 + lane];
        float d  = deg[i];
        float rd = (d == 0.0f) ? 1.0f : (1.0f / d);
        aggN[(size_t)i * CC + lane]      = s0 * rd;
        aggN[(size_t)i * CC + 64 + lane] = s1 * rd;
    }
}

// ---------------------------------------------------------------------------
// Kernel 2: h = aggN @ Wn^T + X @ Wc^T + bn + bc, fused BN partial sums.
// Fused LDS array Wp[swz(k*128+c)] = bf16(Wn)|bf16(Wc)<<16, XOR swizzle
// ^(k&31): conflict-free reads, one ds_read_b32 per (k, both weights).
// (unchanged — verified -13.7 us in R3; cooperative fusion reverted: R8
// showed hipLaunchCooperativeKernel costs ~55 us under graph capture)
// ---------------------------------------------------------------------------
__global__ __launch_bounds__(256, 2) void k2_gemm(
        const float* __restrict__ aggN, const float* __restrict__ X,
        const float* __restrict__ Wn, const float* __restrict__ bn,
        const float* __restrict__ Wc, const float* __restrict__ bc,
        float* __restrict__ h, float* __restrict__ bsum, float* __restrict__ bsq) {
    __shared__ unsigned int Wp[128 * 128];      // 64 KB -> 2 blocks/CU
    const int tid = threadIdx.x;
    for (int idx = tid * 4; idx < 128 * 128; idx += 1024) {
        float4 wn4 = *reinterpret_cast<const float4*>(Wn + idx);
        float4 wc4 = *reinterpret_cast<const float4*>(Wc + idx);
        int c = idx >> 7, k0 = idx & 127;       // 4 consecutive k, same c
        #pragma unroll
        for (int q = 0; q < 4; ++q) {
            unsigned int pk = (unsigned int)f2bf((&wn4.x)[q])
                            | ((unsigned int)f2bf((&wc4.x)[q]) << 16);
            int k = k0 + q;
            Wp[(k * 128 + c) ^ (k & 31)] = pk;
        }
    }
    __syncthreads();
    const int c  = tid & 127;
    const int rg = tid >> 7;
    const int i0 = blockIdx.x * 16 + rg * 8;

    float accN[8], accC[8];
    #pragma unroll
    for (int r = 0; r < 8; ++r) { accN[r] = 0.0f; accC[r] = 0.0f; }

    float4 ar[8], xr[8], an[8], xn[8];

#define LOADK(ab_, xb_, k_) do {                                               \
    _Pragma("unroll")                                                          \
    for (int r = 0; r < 8; ++r) {                                              \
        ab_[r] = *reinterpret_cast<const float4*>(&aggN[(size_t)(i0 + r) * CC + (k_)]); \
        xb_[r] = *reinterpret_cast<const float4*>(&X[(size_t)(i0 + r) * CC + (k_)]);    \
    }                                                                          \
} while (0)

#define COMPK(ab_, xb_, k_) do {                                               \
    _Pragma("unroll")                                                          \
    for (int kk = 0; kk < 4; ++kk) {                                           \
        int kq_ = (k_) + kk;                                                   \
        unsigned int pk_ = Wp[(kq_ * 128 + c) ^ (kq_ & 31)];                   \
        float wn_ = __uint_as_float(pk_ << 16);                                \
        float wc_ = __uint_as_float(pk_ & 0xffff0000u);                        \
        _Pragma("unroll")                                                      \
        for (int r = 0; r < 8; ++r) {                                          \
            accN[r] = fmaf((&ab_[r].x)[kk], wn_, accN[r]);                     \
            accC[r] = fmaf((&xb_[r].x)[kk], wc_, accC[r]);                     \
        }                                                                      \
    }                                                                          \
} while (0)

    LOADK(ar, xr, 0);
    for (int k = 0; k < 128; k += 8) {
        LOADK(an, xn, k + 4);
        COMPK(ar, xr, k);
        if (k + 8 < 128) LOADK(ar, xr, k + 8);
        COMPK(an, xn, k + 4);
    }

    const float bnc = bn[c], bcc = bc[c];
    float sp = 0.0f, sq = 0.0f;
    #pragma unroll
    for (int r = 0; r < 8; ++r) {
        float hv = accN[r] + accC[r] + bnc + bcc;
        h[(size_t)(i0 + r) * CC + c] = hv;
        sp += hv; sq += hv * hv;
    }
    __syncthreads();                              // Wp reads done; reuse as fp32 scratch
    float* red = reinterpret_cast<float*>(Wp);
    red[rg * 128 + c]       = sp;
    red[256 + rg * 128 + c] = sq;
    __syncthreads();
    if (rg == 0) {
        atomicAdd(&bsum[c], red[c] + red[128 + c]);
        atomicAdd(&bsq[c],  red[256 + c] + red[384 + c]);
    }
}

// ---------------------------------------------------------------------------
// Kernel 3: out = relu(gamma * (h - mu) * rsqrt(var + eps) + beta), float4.
// ---------------------------------------------------------------------------
__global__ __launch_bounds__(256) void k4_bn(
        const float* __restrict__ h, const float* __restrict__ bsum,
        const float* __restrict__ bsq, const float* __restrict__ gamma,
        const float* __restrict__ beta, float* __restrict__ out) {
    const int idx = (blockIdx.x * 256 + threadIdx.x) * 4;
    const int c0  = idx & 127;
    float4 hv = *reinterpret_cast<const float4*>(h + idx);
    float4 s4 = *reinterpret_cast<const float4*>(bsum + c0);
    float4 q4 = *reinterpret_cast<const float4*>(bsq + c0);
    float4 g4 = *reinterpret_cast<const float4*>(gamma + c0);
    float4 b4 = *reinterpret_cast<const float4*>(beta + c0);
    const float invN = 1.0f / 8192.0f;
    float4 o;
    const float* hp = &hv.x; const float* sp = &s4.x; const float* qp = &q4.x;
    const float* gp = &g4.x; const float* bp = &b4.x; float* op = &o.x;
    #pragma unroll
    for (int jj = 0; jj < 4; ++jj) {
        float mu  = sp[jj] * invN;
        float var = qp[jj] * invN - mu * mu;
        float sc  = gp[jj] * rsqrtf(var + BN_EPS);
        float v   = (hp[jj] - mu) * sc + bp[jj];
        op[jj] = v > 0.0f ? v : 0.0f;
    }
    *reinterpret_cast<float4*>(out + idx) = o;
}

extern "C" void kernel_launch(void* const* d_in, const int* in_sizes, int n_in,
                              void* d_out, int out_size, void* d_ws, size_t ws_size,
                              hipStream_t stream) {
    const float* X     = (const float*)d_in[0];   // [8192,128]
    const float* A     = (const float*)d_in[1];   // [8192,8192]
    const float* Wn    = (const float*)d_in[2];   // [128,128]
    const float* bn    = (const float*)d_in[3];
    const float* Wc    = (const float*)d_in[4];
    const float* bc    = (const float*)d_in[5];
    const float* gamma = (const float*)d_in[6];
    const float* beta  = (const float*)d_in[7];
    float* out = (float*)d_out;

    // Workspace layout (12.65 MB) — identical to round 3:
    //   deg   @ 0        (32 KB, zeroed)
    //   bsum  @ 32768    (512 B, zeroed)
    //   bsq   @ 33280    (512 B, zeroed)
    //   aggN  @ 65536    (4 MB, fully written by k1c)
    //   Mt2   @ 4259840  (8 MB, fully written by k1a; [i][band] layout)
    //   h     aliases Mt2 (dead after k1c; k2 writes h before k4 reads)
    char* ws = (char*)d_ws;
    float* deg  = (float*)(ws);
    float* bsum = (float*)(ws + 32768);
    float* bsq  = (float*)(ws + 33280);
    float* aggN = (float*)(ws + 65536);
    unsigned long long* Mt2 = (unsigned long long*)(ws + 4259840);
    float* h    = (float*)(ws + 4259840);

    hipMemsetAsync(d_ws, 0, 33792, stream);

    k1a_mask  <<<2048, 256, 0, stream>>>(A, Mt2, deg);
    k1c_gather<<<8192, 256, 0, stream>>>(Mt2, X, deg, aggN);
    k2_gemm   <<<512,  256, 0, stream>>>(aggN, X, Wn, bn, Wc, bc, h, bsum, bsq);
    k4_bn     <<<1024, 256, 0, stream>>>(h, bsum, bsq, gamma, beta, out);
}